// Round 10
// baseline (493.864 us; speedup 1.0000x reference)
//
#include <hip/hip_runtime.h>
#include <math.h>

// ---------------------------------------------------------------------------
// PiTWithCoords: position-attention transformer on fixed grids.
//  * m_dist EXACT in fp32: d_int / 2^S (down S=13, proc S=11, up S=13).
//  * percentile mask == integer threshold on d_int (order statistic),
//    computed via 4 joint binary searches INSIDE k_klist2 (R9).
//  * att weights input/batch-independent; down/proc = sparse gather with
//    precomputed normalized weights; h in low block bits (XCD locality).
//  * UP attention separable (Kronecker): O = Ay*(Ax*V), den = Sx*Sy.
//  * All GEMMs split-bf16 MFMA (a=hi+lo, 3x mfma_f32_16x16x32_bf16).
//  * R9: fc2 fused into dec-fc1 epilogue (shfl reduce + atomicAdd);
//    thresholds fused into klist2; up_s1 split 2x for occupancy.
// ---------------------------------------------------------------------------

#define PI_F 3.14159265358979323846f

typedef __attribute__((ext_vector_type(8))) short short8;
typedef __attribute__((ext_vector_type(4))) float float4v;
typedef __attribute__((ext_vector_type(4))) unsigned short ushort4v;

__device__ __forceinline__ float gelu_f(float x) {
  float u = 0.7978845608028654f * (x + 0.044715f * x * x * x);
  float e = __expf(2.0f * u);
  float t = 1.0f - 2.0f / (e + 1.0f);
  return 0.5f * x * (1.0f + t);
}

__device__ __forceinline__ float head_scale(float r) {
  return tanf(0.25f * PI_F * (1.0f - 1e-7f) * (1.0f + sinf(r)));
}

__device__ __forceinline__ unsigned short f2bf(float f) {
  union { float f; unsigned u; } c; c.f = f;
  unsigned u = c.u + 0x7FFFu + ((c.u >> 16) & 1u);
  return (unsigned short)(u >> 16);
}
__device__ __forceinline__ float bf2f(unsigned short h) {
  union { unsigned u; float f; } c; c.u = ((unsigned)h) << 16;
  return c.f;
}
__device__ __forceinline__ void split_bf(float f, unsigned short& hi,
                                         unsigned short& lo) {
  hi = f2bf(f);
  lo = f2bf(f - bf2f(hi));
}

// ---------------------------------------------------------------------------
// Encoder -> bf16 hi/lo activations.
// ---------------------------------------------------------------------------
__global__ __launch_bounds__(256) void k_enc(
    const float* __restrict__ x, const float* __restrict__ w,
    const float* __restrict__ b, unsigned short* __restrict__ ahi,
    unsigned short* __restrict__ alo) {
  int row = blockIdx.x;
  int o = threadIdx.x;
  float4 xv = *(const float4*)(x + (size_t)row * 4);
  float4 wv = *(const float4*)(w + (size_t)o * 4);
  float s = xv.x * wv.x + xv.y * wv.y + xv.z * wv.z + xv.w * wv.w + b[o];
  s = gelu_f(s);
  unsigned short hi, lo;
  split_bf(s, hi, lo);
  ahi[(size_t)row * 256 + o] = hi;
  alo[(size_t)row * 256 + o] = lo;
}

// ---------------------------------------------------------------------------
// One-shot weight splitter. dst layout [n][k] ushort hi/lo, segments:
//  down@0(64K) de1@65536 up@131072 pa@196608(4x64K) mlp1@458752 mlp2@720896
//  res@983040; total 1245184 elems. grid 4864 x 256.
// ---------------------------------------------------------------------------
__global__ __launch_bounds__(256) void k_split_all(
    const float* __restrict__ down_w, const float* __restrict__ de1_w,
    const float* __restrict__ up_w, const float* __restrict__ pa_w,
    const float* __restrict__ mlp1_w, const float* __restrict__ mlp2_w,
    const float* __restrict__ res_w, unsigned short* __restrict__ whi,
    unsigned short* __restrict__ wlo) {
  int i = blockIdx.x * 256 + threadIdx.x;
  float f;
  if (i < 65536) {
    int n = i >> 8, k = i & 255;
    f = down_w[(n >> 5) * 8192 + k * 32 + (n & 31)];
  } else if (i < 131072) {
    f = de1_w[i - 65536];
  } else if (i < 196608) {
    int j = i - 131072;
    int n = j >> 8, k = j & 255;
    f = up_w[(n >> 5) * 8192 + k * 32 + (n & 31)];
  } else if (i < 458752) {
    int j = i - 196608;
    int blk = j >> 16, r = j & 65535;
    int n = r >> 8, k = r & 255;
    f = pa_w[(size_t)blk * 65536 + (n >> 5) * 8192 + k * 32 + (n & 31)];
  } else if (i < 720896) {
    f = mlp1_w[i - 458752];
  } else if (i < 983040) {
    f = mlp2_w[i - 720896];
  } else {
    f = res_w[i - 983040];
  }
  unsigned short hi, lo;
  split_bf(f, hi, lo);
  whi[i] = hi;
  wlo[i] = lo;
}

// ---------------------------------------------------------------------------
// 2x2-q-tile union key list + per-(h,tile,cell) float4 of normalized weights
// (w_i = 0 for cells outside disc i). One block per tile (16x16 tiles).
// R9: the 4 per-q order-statistic thresholds are computed inline via joint
// binary search over register-cached integer distances (NPT cells/thread).
// ---------------------------------------------------------------------------
template <int KRES, int CXM, int DSHIFT, int J2, int NPT, int TARGET,
          int ITERS, int TMAX>
__global__ __launch_bounds__(256) void k_klist2(
    const float* __restrict__ rvec, int* __restrict__ klist2,
    int* __restrict__ kcnt2, float* __restrict__ wlist2) {
  __shared__ int cntS;
  __shared__ int sidx[J2];
  __shared__ int sdv[J2][4];
  __shared__ float denS[8][4];
  __shared__ int wsum4[4][4];
  int tile = blockIdx.x, tid = threadIdx.x;
  int tx = tile & 15, ty = tile >> 4;
  int cxA[4], cyA[4];
#pragma unroll
  for (int i = 0; i < 4; ++i) {
    int qx = 2 * tx + (i & 1), qy = 2 * ty + (i >> 1);
    cxA[i] = qx * CXM; cyA[i] = qy * CXM;
  }
  // --- fused order-statistic thresholds (4 joint binary searches) ---
  int dc[4][NPT];
#pragma unroll
  for (int j = 0; j < NPT; ++j) {
    int p = tid * NPT + j;
    int kx = p & (KRES - 1), ky = p / KRES;
#pragma unroll
    for (int i = 0; i < 4; ++i) {
      int dx = cxA[i] - kx, dy = cyA[i] - ky;
      dc[i][j] = dx * dx + dy * dy;
    }
  }
  int lo4[4] = {0, 0, 0, 0}, hi4[4] = {TMAX, TMAX, TMAX, TMAX};
  for (int it = 0; it < ITERS; ++it) {
    int mid[4], c[4] = {0, 0, 0, 0};
#pragma unroll
    for (int i = 0; i < 4; ++i) {
      mid[i] = (lo4[i] + hi4[i]) >> 1;
      if (lo4[i] < hi4[i]) {
#pragma unroll
        for (int j = 0; j < NPT; ++j) c[i] += (dc[i][j] <= mid[i]) ? 1 : 0;
      }
    }
#pragma unroll
    for (int i = 0; i < 4; ++i)
#pragma unroll
      for (int off = 32; off > 0; off >>= 1)
        c[i] += __shfl_down(c[i], off, 64);
    if ((tid & 63) == 0) {
#pragma unroll
      for (int i = 0; i < 4; ++i) wsum4[tid >> 6][i] = c[i];
    }
    __syncthreads();
#pragma unroll
    for (int i = 0; i < 4; ++i) {
      if (lo4[i] < hi4[i]) {
        int tot = wsum4[0][i] + wsum4[1][i] + wsum4[2][i] + wsum4[3][i];
        if (tot >= TARGET) hi4[i] = mid[i]; else lo4[i] = mid[i] + 1;
      }
    }
    __syncthreads();
  }
  int T[4];
#pragma unroll
  for (int i = 0; i < 4; ++i) T[i] = lo4[i];
  // --- union key list over the 4 discs ---
  if (tid == 0) cntS = 0;
  __syncthreads();
  int x0 = KRES - 1, x1 = 0, y0 = KRES - 1, y1 = 0;
#pragma unroll
  for (int i = 0; i < 4; ++i) {
    int rad = (int)sqrtf((float)T[i]);
    while ((rad + 1) * (rad + 1) <= T[i]) ++rad;
    while (rad > 0 && rad * rad > T[i]) --rad;
    x0 = min(x0, max(0, cxA[i] - rad));
    x1 = max(x1, min(KRES - 1, cxA[i] + rad));
    y0 = min(y0, max(0, cyA[i] - rad));
    y1 = max(y1, min(KRES - 1, cyA[i] + rad));
  }
  int W = x1 - x0 + 1, H = y1 - y0 + 1, tot = W * H;
  for (int p = tid; p < tot; p += 256) {
    int kx = x0 + p % W, ky = y0 + p / W;
    int d[4]; bool keep = false;
#pragma unroll
    for (int i = 0; i < 4; ++i) {
      int dx = cxA[i] - kx, dy = cyA[i] - ky;
      d[i] = dx * dx + dy * dy;
      keep = keep || (d[i] <= T[i]);
    }
    if (keep) {
      int s = atomicAdd(&cntS, 1);
      if (s < J2) {
        sidx[s] = ky * KRES + kx;
#pragma unroll
        for (int i = 0; i < 4; ++i) sdv[s][i] = d[i];
      }
    }
  }
  __syncthreads();
  int cnt = min(cntS, J2);
  int h = tid >> 5, lane = tid & 31;
  float sc = head_scale(rvec[h]) * (1.0f / (float)(1 << DSHIFT));
  float den[4] = {0.f, 0.f, 0.f, 0.f};
  for (int j = lane; j < cnt; j += 32) {
#pragma unroll
    for (int i = 0; i < 4; ++i)
      if (sdv[j][i] <= T[i]) den[i] += __expf(-sc * (float)sdv[j][i]);
  }
#pragma unroll
  for (int i = 0; i < 4; ++i) {
    float d0 = den[i];
#pragma unroll
    for (int off = 16; off > 0; off >>= 1) d0 += __shfl_down(d0, off, 32);
    if (lane == 0) denS[h][i] = d0;
  }
  __syncthreads();
  float inv[4];
#pragma unroll
  for (int i = 0; i < 4; ++i) inv[i] = 1.0f / denS[h][i];
  for (int j = lane; j < cnt; j += 32) {
    float w[4];
#pragma unroll
    for (int i = 0; i < 4; ++i)
      w[i] = (sdv[j][i] <= T[i]) ? __expf(-sc * (float)sdv[j][i]) * inv[i] : 0.f;
    float4v wv = {w[0], w[1], w[2], w[3]};
    *(float4v*)&wlist2[(((size_t)h * 256 + tile) * J2 + j) * 4] = wv;
  }
  if (tid == 0) kcnt2[tile] = cnt;
  if (h == 0)
    for (int j = lane; j < cnt; j += 32) klist2[(size_t)tile * J2 + j] = sidx[j];
}

// ---------------------------------------------------------------------------
// Tiled sparse attention: block = (2x2 q-tile, h), h in low bits (XCD).
// ---------------------------------------------------------------------------
template <int NK, int J2>
__global__ __launch_bounds__(256) void k_att3(
    const float* __restrict__ value,   // [h][NK][b*32+v]
    const int* __restrict__ klist2, const int* __restrict__ kcnt2,
    const float* __restrict__ wlist2, unsigned short* __restrict__ ohi,
    unsigned short* __restrict__ olo) {
  __shared__ int kls[J2];
  __shared__ float4v wls[J2];
  __shared__ float4v part[4][4][64];
  int blk = blockIdx.x;
  int tile = blk >> 3, h = blk & 7;
  int tid = threadIdx.x, g = tid & 63, s = tid >> 6;
  int cnt = kcnt2[tile];
  for (int j = tid; j < cnt; j += 256) {
    kls[j] = klist2[(size_t)tile * J2 + j];
    wls[j] = *(const float4v*)&wlist2[(((size_t)h * 256 + tile) * J2 + j) * 4];
  }
  __syncthreads();
  const float* vb = value + (size_t)h * NK * 256 + g * 4;
  float4v acc[4];
#pragma unroll
  for (int i = 0; i < 4; ++i) acc[i] = (float4v)0.0f;
  for (int j = s; j < cnt; j += 4) {
    int row = kls[j];
    float4v v = *(const float4v*)(vb + (size_t)row * 256);
    float4v w = wls[j];
    acc[0] += w.x * v;
    acc[1] += w.y * v;
    acc[2] += w.z * v;
    acc[3] += w.w * v;
  }
#pragma unroll
  for (int i = 0; i < 4; ++i) part[s][i][g] = acc[i];
  __syncthreads();
  if (tid < 64) {
    int g2 = tid;
    int ttx = tile & 15, tty = tile >> 4;
    int batch = g2 >> 3, v0 = (g2 & 7) * 4;
#pragma unroll
    for (int i = 0; i < 4; ++i) {
      float4v o4 = part[0][i][g2] + part[1][i][g2] + part[2][i][g2] +
                   part[3][i][g2];
      int q = (2 * tty + (i >> 1)) * 32 + 2 * ttx + (i & 1);
      size_t idx = ((size_t)batch * 1024 + q) * 256 + h * 32 + v0;
      ushort4v hv, lv;
#pragma unroll
      for (int c = 0; c < 4; ++c) {
        float oo = gelu_f(o4[c]);
        unsigned short hi, lo;
        split_bf(oo, hi, lo);
        hv[c] = hi; lv[c] = lo;
      }
      *(ushort4v*)(ohi + idx) = hv;
      *(ushort4v*)(olo + idx) = lv;
    }
  }
}

// ---------------------------------------------------------------------------
// Split-bf16 MFMA GEMM, 128x128 tile (big GEMMs, M=32768).
// ---------------------------------------------------------------------------
template <bool DUAL, int OL, bool GEL, bool OHILO>
__global__ __launch_bounds__(256) void k_mf(
    const unsigned short* __restrict__ A1hi, const unsigned short* __restrict__ A1lo,
    const unsigned short* __restrict__ W1hi, const unsigned short* __restrict__ W1lo,
    const unsigned short* __restrict__ A2hi, const unsigned short* __restrict__ A2lo,
    const unsigned short* __restrict__ W2hi, const unsigned short* __restrict__ W2lo,
    const float* __restrict__ bias, const float* __restrict__ bias2,
    float* __restrict__ outf, unsigned short* __restrict__ ohi,
    unsigned short* __restrict__ olo, int NS) {
  __shared__ unsigned short Ah[128][40], Al[128][40];
  __shared__ unsigned short Bh[128][40], Bl[128][40];
  int tid = threadIdx.x;
  int m0 = blockIdx.x * 128, n0 = blockIdx.y * 128;
  int w = tid >> 6, lane = tid & 63;
  int wm = (w >> 1) * 64, wn = (w & 1) * 64;
  int quad = lane >> 4, l16 = lane & 15;
  float4v acc[4][4];
#pragma unroll
  for (int i = 0; i < 4; ++i)
#pragma unroll
    for (int j = 0; j < 4; ++j) acc[i][j] = (float4v)0.0f;

  int srow = tid >> 1, skq = (tid & 1) * 16;
  const int KT = DUAL ? 512 : 256;
  for (int kk = 0; kk < KT; kk += 32) {
    const unsigned short *pAh, *pAl, *pWh, *pWl;
    int kb;
    if (DUAL && kk >= 256) {
      pAh = A2hi; pAl = A2lo; pWh = W2hi; pWl = W2lo; kb = kk - 256;
    } else {
      pAh = A1hi; pAl = A1lo; pWh = W1hi; pWl = W1lo; kb = kk;
    }
    {
      size_t ga = (size_t)(m0 + srow) * 256 + kb + skq;
      const uint4* pah = (const uint4*)(pAh + ga);
      const uint4* pal = (const uint4*)(pAl + ga);
      *(uint4*)&Ah[srow][skq] = pah[0];
      *(uint4*)&Ah[srow][skq + 8] = pah[1];
      *(uint4*)&Al[srow][skq] = pal[0];
      *(uint4*)&Al[srow][skq + 8] = pal[1];
      size_t gb = (size_t)(n0 + srow) * 256 + kb + skq;
      const uint4* pbh = (const uint4*)(pWh + gb);
      const uint4* pbl = (const uint4*)(pWl + gb);
      *(uint4*)&Bh[srow][skq] = pbh[0];
      *(uint4*)&Bh[srow][skq + 8] = pbh[1];
      *(uint4*)&Bl[srow][skq] = pbl[0];
      *(uint4*)&Bl[srow][skq + 8] = pbl[1];
    }
    __syncthreads();
    short8 ah[4], al[4], bh[4], bl[4];
#pragma unroll
    for (int s = 0; s < 4; ++s) {
      ah[s] = *(const short8*)&Ah[wm + s * 16 + l16][quad * 8];
      al[s] = *(const short8*)&Al[wm + s * 16 + l16][quad * 8];
      bh[s] = *(const short8*)&Bh[wn + s * 16 + l16][quad * 8];
      bl[s] = *(const short8*)&Bl[wn + s * 16 + l16][quad * 8];
    }
#pragma unroll
    for (int ms = 0; ms < 4; ++ms)
#pragma unroll
      for (int ns = 0; ns < 4; ++ns) {
        acc[ms][ns] = __builtin_amdgcn_mfma_f32_16x16x32_bf16(
            ah[ms], bh[ns], acc[ms][ns], 0, 0, 0);
        acc[ms][ns] = __builtin_amdgcn_mfma_f32_16x16x32_bf16(
            ah[ms], bl[ns], acc[ms][ns], 0, 0, 0);
        acc[ms][ns] = __builtin_amdgcn_mfma_f32_16x16x32_bf16(
            al[ms], bh[ns], acc[ms][ns], 0, 0, 0);
      }
    __syncthreads();
  }
#pragma unroll
  for (int ms = 0; ms < 4; ++ms) {
#pragma unroll
    for (int ns = 0; ns < 4; ++ns) {
      int n = n0 + wn + ns * 16 + l16;
      float bv = bias ? bias[n] : 0.0f;
      if (DUAL && bias2) bv += bias2[n];
#pragma unroll
      for (int r = 0; r < 4; ++r) {
        int m = m0 + wm + ms * 16 + quad * 4 + r;
        float c = acc[ms][ns][r] + bv;
        if (GEL) c = gelu_f(c);
        if (OHILO) {
          unsigned short chi, clo;
          split_bf(c, chi, clo);
          ohi[(size_t)m * 256 + n] = chi;
          olo[(size_t)m * 256 + n] = clo;
        } else if (OL == 0) {
          outf[(size_t)m * 256 + n] = c;
        } else {
          int N = 1 << NS;
          int bb = m >> NS, rr = m & (N - 1);
          outf[(((size_t)(n >> 5) * N + rr) * 8 + bb) * 32 + (n & 31)] = c;
        }
      }
    }
  }
}

// ---------------------------------------------------------------------------
// Decoder fc1+fc2 fused: same 128x128 MFMA core; epilogue computes
// sum_n gelu(fc1[m,n]+b1[n])*w2[n] via 16-lane shfl_xor reduce, then
// atomicAdd into out[m] (pre-initialized to b2 by k_init_out).
// ---------------------------------------------------------------------------
__global__ __launch_bounds__(256) void k_mf_dec(
    const unsigned short* __restrict__ A1hi, const unsigned short* __restrict__ A1lo,
    const unsigned short* __restrict__ W1hi, const unsigned short* __restrict__ W1lo,
    const float* __restrict__ b1, const float* __restrict__ w2,
    float* __restrict__ out) {
  __shared__ unsigned short Ah[128][40], Al[128][40];
  __shared__ unsigned short Bh[128][40], Bl[128][40];
  int tid = threadIdx.x;
  int m0 = blockIdx.x * 128, n0 = blockIdx.y * 128;
  int w = tid >> 6, lane = tid & 63;
  int wm = (w >> 1) * 64, wn = (w & 1) * 64;
  int quad = lane >> 4, l16 = lane & 15;
  float4v acc[4][4];
#pragma unroll
  for (int i = 0; i < 4; ++i)
#pragma unroll
    for (int j = 0; j < 4; ++j) acc[i][j] = (float4v)0.0f;

  int srow = tid >> 1, skq = (tid & 1) * 16;
  for (int kk = 0; kk < 256; kk += 32) {
    {
      size_t ga = (size_t)(m0 + srow) * 256 + kk + skq;
      const uint4* pah = (const uint4*)(A1hi + ga);
      const uint4* pal = (const uint4*)(A1lo + ga);
      *(uint4*)&Ah[srow][skq] = pah[0];
      *(uint4*)&Ah[srow][skq + 8] = pah[1];
      *(uint4*)&Al[srow][skq] = pal[0];
      *(uint4*)&Al[srow][skq + 8] = pal[1];
      size_t gb = (size_t)(n0 + srow) * 256 + kk + skq;
      const uint4* pbh = (const uint4*)(W1hi + gb);
      const uint4* pbl = (const uint4*)(W1lo + gb);
      *(uint4*)&Bh[srow][skq] = pbh[0];
      *(uint4*)&Bh[srow][skq + 8] = pbh[1];
      *(uint4*)&Bl[srow][skq] = pbl[0];
      *(uint4*)&Bl[srow][skq + 8] = pbl[1];
    }
    __syncthreads();
    short8 ah[4], al[4], bh[4], bl[4];
#pragma unroll
    for (int s = 0; s < 4; ++s) {
      ah[s] = *(const short8*)&Ah[wm + s * 16 + l16][quad * 8];
      al[s] = *(const short8*)&Al[wm + s * 16 + l16][quad * 8];
      bh[s] = *(const short8*)&Bh[wn + s * 16 + l16][quad * 8];
      bl[s] = *(const short8*)&Bl[wn + s * 16 + l16][quad * 8];
    }
#pragma unroll
    for (int ms = 0; ms < 4; ++ms)
#pragma unroll
      for (int ns = 0; ns < 4; ++ns) {
        acc[ms][ns] = __builtin_amdgcn_mfma_f32_16x16x32_bf16(
            ah[ms], bh[ns], acc[ms][ns], 0, 0, 0);
        acc[ms][ns] = __builtin_amdgcn_mfma_f32_16x16x32_bf16(
            ah[ms], bl[ns], acc[ms][ns], 0, 0, 0);
        acc[ms][ns] = __builtin_amdgcn_mfma_f32_16x16x32_bf16(
            al[ms], bh[ns], acc[ms][ns], 0, 0, 0);
      }
    __syncthreads();
  }
#pragma unroll
  for (int ms = 0; ms < 4; ++ms) {
#pragma unroll
    for (int r = 0; r < 4; ++r) {
      float p = 0.0f;
#pragma unroll
      for (int ns = 0; ns < 4; ++ns) {
        int n = n0 + wn + ns * 16 + l16;
        float c = gelu_f(acc[ms][ns][r] + b1[n]);
        p += c * w2[n];
      }
      p += __shfl_xor(p, 1, 64);
      p += __shfl_xor(p, 2, 64);
      p += __shfl_xor(p, 4, 64);
      p += __shfl_xor(p, 8, 64);
      if (l16 == 0) {
        int m = m0 + wm + ms * 16 + quad * 4 + r;
        atomicAdd(&out[m], p);
      }
    }
  }
}

__global__ __launch_bounds__(256) void k_init_out(float* __restrict__ out,
                                                  const float* __restrict__ b) {
  out[blockIdx.x * 256 + threadIdx.x] = b[0];
}

// ---------------------------------------------------------------------------
// Split-bf16 MFMA GEMM, 64x64 tile (medium GEMMs, M=8192 -> 512 blocks).
// ---------------------------------------------------------------------------
template <bool DUAL, int OL, bool GEL, bool OHILO>
__global__ __launch_bounds__(256) void k_mf2(
    const unsigned short* __restrict__ A1hi, const unsigned short* __restrict__ A1lo,
    const unsigned short* __restrict__ W1hi, const unsigned short* __restrict__ W1lo,
    const unsigned short* __restrict__ A2hi, const unsigned short* __restrict__ A2lo,
    const unsigned short* __restrict__ W2hi, const unsigned short* __restrict__ W2lo,
    const float* __restrict__ bias, const float* __restrict__ bias2,
    float* __restrict__ outf, unsigned short* __restrict__ ohi,
    unsigned short* __restrict__ olo, int NS) {
  __shared__ unsigned short Ah[64][40], Al[64][40];
  __shared__ unsigned short Bh[64][40], Bl[64][40];
  int tid = threadIdx.x;
  int m0 = blockIdx.x * 64, n0 = blockIdx.y * 64;
  int w = tid >> 6, lane = tid & 63;
  int wm = (w >> 1) * 32, wn = (w & 1) * 32;
  int quad = lane >> 4, l16 = lane & 15;
  float4v acc[2][2];
#pragma unroll
  for (int i = 0; i < 2; ++i)
#pragma unroll
    for (int j = 0; j < 2; ++j) acc[i][j] = (float4v)0.0f;

  int srow = tid >> 2, skq = (tid & 3) * 8;
  const int KT = DUAL ? 512 : 256;
  for (int kk = 0; kk < KT; kk += 32) {
    const unsigned short *pAh, *pAl, *pWh, *pWl;
    int kb;
    if (DUAL && kk >= 256) {
      pAh = A2hi; pAl = A2lo; pWh = W2hi; pWl = W2lo; kb = kk - 256;
    } else {
      pAh = A1hi; pAl = A1lo; pWh = W1hi; pWl = W1lo; kb = kk;
    }
    {
      size_t ga = (size_t)(m0 + srow) * 256 + kb + skq;
      *(uint4*)&Ah[srow][skq] = *(const uint4*)(pAh + ga);
      *(uint4*)&Al[srow][skq] = *(const uint4*)(pAl + ga);
      size_t gb = (size_t)(n0 + srow) * 256 + kb + skq;
      *(uint4*)&Bh[srow][skq] = *(const uint4*)(pWh + gb);
      *(uint4*)&Bl[srow][skq] = *(const uint4*)(pWl + gb);
    }
    __syncthreads();
    short8 ah[2], al[2], bh[2], bl[2];
#pragma unroll
    for (int s = 0; s < 2; ++s) {
      ah[s] = *(const short8*)&Ah[wm + s * 16 + l16][quad * 8];
      al[s] = *(const short8*)&Al[wm + s * 16 + l16][quad * 8];
      bh[s] = *(const short8*)&Bh[wn + s * 16 + l16][quad * 8];
      bl[s] = *(const short8*)&Bl[wn + s * 16 + l16][quad * 8];
    }
#pragma unroll
    for (int ms = 0; ms < 2; ++ms)
#pragma unroll
      for (int ns = 0; ns < 2; ++ns) {
        acc[ms][ns] = __builtin_amdgcn_mfma_f32_16x16x32_bf16(
            ah[ms], bh[ns], acc[ms][ns], 0, 0, 0);
        acc[ms][ns] = __builtin_amdgcn_mfma_f32_16x16x32_bf16(
            ah[ms], bl[ns], acc[ms][ns], 0, 0, 0);
        acc[ms][ns] = __builtin_amdgcn_mfma_f32_16x16x32_bf16(
            al[ms], bh[ns], acc[ms][ns], 0, 0, 0);
      }
    __syncthreads();
  }
#pragma unroll
  for (int ms = 0; ms < 2; ++ms) {
#pragma unroll
    for (int ns = 0; ns < 2; ++ns) {
      int n = n0 + wn + ns * 16 + l16;
      float bv = bias ? bias[n] : 0.0f;
      if (DUAL && bias2) bv += bias2[n];
#pragma unroll
      for (int r = 0; r < 4; ++r) {
        int m = m0 + wm + ms * 16 + quad * 4 + r;
        float c = acc[ms][ns][r] + bv;
        if (GEL) c = gelu_f(c);
        if (OHILO) {
          unsigned short chi, clo;
          split_bf(c, chi, clo);
          ohi[(size_t)m * 256 + n] = chi;
          olo[(size_t)m * 256 + n] = clo;
        } else if (OL == 0) {
          outf[(size_t)m * 256 + n] = c;
        } else {
          int N = 1 << NS;
          int bb = m >> NS, rr = m & (N - 1);
          outf[(((size_t)(n >> 5) * N + rr) * 8 + bb) * 32 + (n & 31)] = c;
        }
      }
    }
  }
}

// ---------------------------------------------------------------------------
// Separable up-attention stage 1: T[h][qx][ky][bv] = sum_kx Ax[qx][kx]*V.
// R9: qx split across blockIdx.z (2x) for occupancy (512 blocks = 2/CU).
// ---------------------------------------------------------------------------
__global__ __launch_bounds__(256) void k_up_s1(
    const float* __restrict__ value,  // [h][1024][bv]
    const float* __restrict__ rvec, float* __restrict__ T) {
  __shared__ float AxL[32][33];
  int ky = blockIdx.x, h = blockIdx.y, qx0 = blockIdx.z * 32;
  int tid = threadIdx.x;
  float sc = head_scale(rvec[h]) * (1.0f / 8192.0f);
  float v[32];
  const float* vb = value + ((size_t)h * 1024 + ky * 32) * 256 + tid;
#pragma unroll
  for (int kx = 0; kx < 32; ++kx) v[kx] = vb[kx * 256];
  if (tid < 32) {
    int qx = qx0 + tid, dxmin = qx & 1;
    for (int kx = 0; kx < 32; ++kx) {
      int dx = qx - 2 * kx;
      AxL[tid][kx] = __expf(-sc * (float)(dx * dx - dxmin));
    }
  }
  __syncthreads();
  for (int qq = 0; qq < 32; ++qq) {
    int qx = qx0 + qq;
    float acc = 0.f;
#pragma unroll
    for (int kx = 0; kx < 32; ++kx) acc += AxL[qq][kx] * v[kx];
    T[(((size_t)h * 64 + qx) * 32 + ky) * 256 + tid] = acc;
  }
}

// ---------------------------------------------------------------------------
// Separable up-attention stage 2 -> bf16 hi/lo (feeds dec-fc1 MFMA).
// ---------------------------------------------------------------------------
__global__ __launch_bounds__(256) void k_up_s2(
    const float* __restrict__ T, const float* __restrict__ rvec,
    unsigned short* __restrict__ ohi, unsigned short* __restrict__ olo) {
  __shared__ float AyL[64][33];
  __shared__ float Sy[64];
  __shared__ float SxS;
  int qx = blockIdx.x, h = blockIdx.y, tid = threadIdx.x;
  float sc = head_scale(rvec[h]) * (1.0f / 8192.0f);
  float t[32];
  const float* tb = T + ((size_t)h * 64 + qx) * 32 * 256 + tid;
#pragma unroll
  for (int ky = 0; ky < 32; ++ky) t[ky] = tb[ky * 256];
  if (tid < 64) {
    int qy = tid, dymin = qy & 1;
    float s = 0.f;
    for (int ky = 0; ky < 32; ++ky) {
      int dy = qy - 2 * ky;
      float e = __expf(-sc * (float)(dy * dy - dymin));
      AyL[qy][ky] = e;
      s += e;
    }
    Sy[qy] = s;
  } else if (tid >= 64 && tid < 96) {
    int kx = tid - 64, dxmin = qx & 1;
    int dx = qx - 2 * kx;
    float e = __expf(-sc * (float)(dx * dx - dxmin));
#pragma unroll
    for (int off = 16; off > 0; off >>= 1) e += __shfl_down(e, off, 32);
    if (kx == 0) SxS = e;
  }
  __syncthreads();
  float invSx = 1.0f / SxS;
  int b = tid >> 5, v = tid & 31;
  size_t base = ((size_t)b * 4096 + qx) * 256 + h * 32 + v;
  for (int qy = 0; qy < 64; ++qy) {
    float acc = 0.f;
#pragma unroll
    for (int ky = 0; ky < 32; ++ky) acc += AyL[qy][ky] * t[ky];
    float o = gelu_f(acc * invSx / Sy[qy]);
    unsigned short hi, lo;
    split_bf(o, hi, lo);
    size_t idx = base + (size_t)qy * 64 * 256;
    ohi[idx] = hi;
    olo[idx] = lo;
  }
}

// ---------------------------------------------------------------------------
extern "C" void kernel_launch(void* const* d_in, const int* in_sizes, int n_in,
                              void* d_out, int out_size, void* d_ws,
                              size_t ws_size, hipStream_t stream) {
  const float* x      = (const float*)d_in[0];
  const float* en_w   = (const float*)d_in[1];
  const float* en_b   = (const float*)d_in[2];
  const float* down_r = (const float*)d_in[3];
  const float* down_w = (const float*)d_in[4];
  const float* pa_r   = (const float*)d_in[5];
  const float* pa_w   = (const float*)d_in[6];
  const float* mlp1_w = (const float*)d_in[7];
  const float* mlp1_b = (const float*)d_in[8];
  const float* mlp2_w = (const float*)d_in[9];
  const float* mlp2_b = (const float*)d_in[10];
  const float* res_w  = (const float*)d_in[11];
  const float* res_b  = (const float*)d_in[12];
  const float* up_r   = (const float*)d_in[13];
  const float* up_w   = (const float*)d_in[14];
  const float* de1_w  = (const float*)d_in[15];
  const float* de1_b  = (const float*)d_in[16];
  const float* de2_w  = (const float*)d_in[17];
  const float* de2_b  = (const float*)d_in[18];
  float* out = (float*)d_out;

  constexpr int J2 = 256;
  float* ws = (float*)d_ws;
  // [0, 8388608): enc / up_s2 activations, bf16 hi/lo (32768x256 each)
  unsigned short* Ahi = (unsigned short*)ws;
  unsigned short* Alo = Ahi + 8388608;
  // [8388608, 16777216): B fp32 — down value / proc+up value / T
  float* B = ws + 8388608;
  float* Tbuf = B + 2097152;
  // [16777216, 25165824): 8 activation hi/lo buffers, each 2097152 ushorts
  unsigned short* hAhi = (unsigned short*)(ws + 16777216);
  unsigned short* hAlo = hAhi + 2097152;
  unsigned short* hBhi = hAlo + 2097152;
  unsigned short* hBlo = hBhi + 2097152;
  unsigned short* pahi = hBlo + 2097152;
  unsigned short* palo = pahi + 2097152;
  unsigned short* m1hi = palo + 2097152;
  unsigned short* m1lo = m1hi + 2097152;
  // [25165824, ...): misc — AFTER all activation buffers.
  int* cntD2 = (int*)(ws + 25165824);
  int* cntP2 = cntD2 + 256;
  int* klD2 = cntP2 + 256;              // [256*J2]
  int* klP2 = klD2 + 256 * J2;
  float* wlD2 = (float*)(klP2 + 256 * J2);  // [8*256*J2*4] = 2097152 floats
  float* wlP2 = wlD2 + 2097152;
  unsigned short* Whi = (unsigned short*)(wlP2 + 2097152);  // 1245184 each
  unsigned short* Wlo = Whi + 1245184;
  const int WO_DOWN = 0, WO_DE1 = 65536, WO_UP = 131072, WO_PA = 196608,
            WO_MLP1 = 458752, WO_MLP2 = 720896, WO_RES = 983040;

  // 1. encoder -> bf16 hi/lo
  k_enc<<<32768, 256, 0, stream>>>(x, en_w, en_b, Ahi, Alo);
  // 2. weight splits + tiled key lists w/ fused thresholds
  k_split_all<<<4864, 256, 0, stream>>>(down_w, de1_w, up_w, pa_w, mlp1_w,
                                        mlp2_w, res_w, Whi, Wlo);
  k_klist2<64, 2, 13, J2, 16, 82, 13, 7938><<<256, 256, 0, stream>>>(
      down_r, klD2, cntD2, wlD2);
  k_klist2<32, 1, 11, J2, 4, 103, 11, 1922><<<256, 256, 0, stream>>>(
      pa_r, klP2, cntP2, wlP2);
  // 3. down: value MFMA -> B [h][4096][bv]; tiled sparse att -> hA (hi/lo)
  k_mf<false, 1, false, false><<<dim3(256, 2), 256, 0, stream>>>(
      Ahi, Alo, Whi + WO_DOWN, Wlo + WO_DOWN, nullptr, nullptr, nullptr,
      nullptr, nullptr, nullptr, B, nullptr, nullptr, 12);
  k_att3<4096, J2><<<2048, 256, 0, stream>>>(B, klD2, cntD2, wlD2, hAhi, hAlo);
  // 4. processor blocks, h ping-pong hA <-> hB (64x64-tile MFMA)
  for (int i = 0; i < 4; ++i) {
    const unsigned short* hih = (i & 1) ? hBhi : hAhi;
    const unsigned short* hil = (i & 1) ? hBlo : hAlo;
    unsigned short* hoh = (i & 1) ? hAhi : hBhi;
    unsigned short* hol = (i & 1) ? hAlo : hBlo;
    k_mf2<false, 1, false, false><<<dim3(128, 4), 256, 0, stream>>>(
        hih, hil, Whi + WO_PA + i * 65536, Wlo + WO_PA + i * 65536, nullptr,
        nullptr, nullptr, nullptr, nullptr, nullptr, B, nullptr, nullptr, 10);
    k_att3<1024, J2><<<2048, 256, 0, stream>>>(B, klP2, cntP2, wlP2, pahi,
                                               palo);
    k_mf2<false, 0, true, true><<<dim3(128, 4), 256, 0, stream>>>(
        pahi, palo, Whi + WO_MLP1 + i * 65536, Wlo + WO_MLP1 + i * 65536,
        nullptr, nullptr, nullptr, nullptr, mlp1_b + i * 256, nullptr, nullptr,
        m1hi, m1lo, 0);
    k_mf2<true, 0, true, true><<<dim3(128, 4), 256, 0, stream>>>(
        m1hi, m1lo, Whi + WO_MLP2 + i * 65536, Wlo + WO_MLP2 + i * 65536, hih,
        hil, Whi + WO_RES + i * 65536, Wlo + WO_RES + i * 65536,
        mlp2_b + i * 256, res_b + i * 256, nullptr, hoh, hol, 0);
  }
  // 5. up: value MFMA -> B [h][1024][bv]; separable attention
  k_mf2<false, 1, false, false><<<dim3(128, 4), 256, 0, stream>>>(
      hAhi, hAlo, Whi + WO_UP, Wlo + WO_UP, nullptr, nullptr, nullptr, nullptr,
      nullptr, nullptr, B, nullptr, nullptr, 10);
  k_up_s1<<<dim3(32, 8, 2), 256, 0, stream>>>(B, up_r, Tbuf);
  k_up_s2<<<dim3(64, 8), 256, 0, stream>>>(Tbuf, up_r, Ahi, Alo);
  // 6. decoder: fc1+fc2 fused MFMA (out pre-initialized to b2)
  k_init_out<<<128, 256, 0, stream>>>(out, de2_b);
  k_mf_dec<<<dim3(256, 2), 256, 0, stream>>>(Ahi, Alo, Whi + WO_DE1,
                                             Wlo + WO_DE1, de1_b, de2_w, out);
}

// Round 11
// 491.097 us; speedup vs baseline: 1.0056x; 1.0056x over previous
//
#include <hip/hip_runtime.h>
#include <math.h>

// ---------------------------------------------------------------------------
// PiTWithCoords: position-attention transformer on fixed grids.
//  * m_dist EXACT in fp32: d_int / 2^S (down S=13, proc S=11, up S=13).
//  * percentile mask == integer threshold on d_int (order statistic),
//    computed via joint binary searches inside k_klist (R9).
//  * att weights input/batch-independent; down/proc = sparse gather with
//    precomputed normalized weights; h in low block bits (XCD locality).
//  * UP attention separable (Kronecker): O = Ay*(Ax*V), den = Sx*Sy.
//  * All GEMMs split-bf16 MFMA (a=hi+lo, 3x mfma_f32_16x16x32_bf16).
//  * R10: dispatch-count test — enc+weight-split+out-init merged into k_pre;
//    both klist configs merged into k_klist_all. Hot kernels unchanged.
// ---------------------------------------------------------------------------

#define PI_F 3.14159265358979323846f

typedef __attribute__((ext_vector_type(8))) short short8;
typedef __attribute__((ext_vector_type(4))) float float4v;
typedef __attribute__((ext_vector_type(4))) unsigned short ushort4v;

__device__ __forceinline__ float gelu_f(float x) {
  float u = 0.7978845608028654f * (x + 0.044715f * x * x * x);
  float e = __expf(2.0f * u);
  float t = 1.0f - 2.0f / (e + 1.0f);
  return 0.5f * x * (1.0f + t);
}

__device__ __forceinline__ float head_scale(float r) {
  return tanf(0.25f * PI_F * (1.0f - 1e-7f) * (1.0f + sinf(r)));
}

__device__ __forceinline__ unsigned short f2bf(float f) {
  union { float f; unsigned u; } c; c.f = f;
  unsigned u = c.u + 0x7FFFu + ((c.u >> 16) & 1u);
  return (unsigned short)(u >> 16);
}
__device__ __forceinline__ float bf2f(unsigned short h) {
  union { unsigned u; float f; } c; c.u = ((unsigned)h) << 16;
  return c.f;
}
__device__ __forceinline__ void split_bf(float f, unsigned short& hi,
                                         unsigned short& lo) {
  hi = f2bf(f);
  lo = f2bf(f - bf2f(hi));
}

// ---------------------------------------------------------------------------
// Merged pre-pass: encoder (blocks [0,32768)), weight split ([32768,37632)),
// out init ([37632,37760)). All independent elementwise work.
// ---------------------------------------------------------------------------
__global__ __launch_bounds__(256) void k_pre(
    const float* __restrict__ x, const float* __restrict__ en_w,
    const float* __restrict__ en_b, unsigned short* __restrict__ ahi,
    unsigned short* __restrict__ alo, const float* __restrict__ down_w,
    const float* __restrict__ de1_w, const float* __restrict__ up_w,
    const float* __restrict__ pa_w, const float* __restrict__ mlp1_w,
    const float* __restrict__ mlp2_w, const float* __restrict__ res_w,
    unsigned short* __restrict__ whi, unsigned short* __restrict__ wlo,
    float* __restrict__ out, const float* __restrict__ de2_b) {
  int blk = blockIdx.x;
  int tid = threadIdx.x;
  if (blk < 32768) {
    // encoder -> bf16 hi/lo
    float4 xv = *(const float4*)(x + (size_t)blk * 4);
    float4 wv = *(const float4*)(en_w + (size_t)tid * 4);
    float s = xv.x * wv.x + xv.y * wv.y + xv.z * wv.z + xv.w * wv.w + en_b[tid];
    s = gelu_f(s);
    unsigned short hi, lo;
    split_bf(s, hi, lo);
    ahi[(size_t)blk * 256 + tid] = hi;
    alo[(size_t)blk * 256 + tid] = lo;
  } else if (blk < 37632) {
    // weight splitter, dst [n][k] segments:
    // down@0 de1@65536 up@131072 pa@196608(4x) mlp1@458752 mlp2@720896 res@983040
    int i = (blk - 32768) * 256 + tid;
    float f;
    if (i < 65536) {
      int n = i >> 8, k = i & 255;
      f = down_w[(n >> 5) * 8192 + k * 32 + (n & 31)];
    } else if (i < 131072) {
      f = de1_w[i - 65536];
    } else if (i < 196608) {
      int j = i - 131072;
      int n = j >> 8, k = j & 255;
      f = up_w[(n >> 5) * 8192 + k * 32 + (n & 31)];
    } else if (i < 458752) {
      int j = i - 196608;
      int b2 = j >> 16, r = j & 65535;
      int n = r >> 8, k = r & 255;
      f = pa_w[(size_t)b2 * 65536 + (n >> 5) * 8192 + k * 32 + (n & 31)];
    } else if (i < 720896) {
      f = mlp1_w[i - 458752];
    } else if (i < 983040) {
      f = mlp2_w[i - 720896];
    } else {
      f = res_w[i - 983040];
    }
    unsigned short hi, lo;
    split_bf(f, hi, lo);
    whi[i] = hi;
    wlo[i] = lo;
  } else {
    // out init to fc2 bias (fc2 fused into k_mf_dec via atomicAdd)
    out[(blk - 37632) * 256 + tid] = de2_b[0];
  }
}

// ---------------------------------------------------------------------------
// klist body: 2x2-q-tile union key list + per-(h,tile,cell) float4 of
// normalized weights (0 outside each disc). Thresholds = 4 joint binary
// searches over register-cached integer distances.
// ---------------------------------------------------------------------------
template <int KRES, int CXM, int DSHIFT, int J2, int NPT, int TARGET,
          int ITERS, int TMAX>
__device__ __forceinline__ void klist_body(
    const float* __restrict__ rvec, int* __restrict__ klist2,
    int* __restrict__ kcnt2, float* __restrict__ wlist2, int tile, int tid) {
  __shared__ int cntS;
  __shared__ int sidx[J2];
  __shared__ int sdv[J2][4];
  __shared__ float denS[8][4];
  __shared__ int wsum4[4][4];
  int tx = tile & 15, ty = tile >> 4;
  int cxA[4], cyA[4];
#pragma unroll
  for (int i = 0; i < 4; ++i) {
    int qx = 2 * tx + (i & 1), qy = 2 * ty + (i >> 1);
    cxA[i] = qx * CXM; cyA[i] = qy * CXM;
  }
  int dc[4][NPT];
#pragma unroll
  for (int j = 0; j < NPT; ++j) {
    int p = tid * NPT + j;
    int kx = p & (KRES - 1), ky = p / KRES;
#pragma unroll
    for (int i = 0; i < 4; ++i) {
      int dx = cxA[i] - kx, dy = cyA[i] - ky;
      dc[i][j] = dx * dx + dy * dy;
    }
  }
  int lo4[4] = {0, 0, 0, 0}, hi4[4] = {TMAX, TMAX, TMAX, TMAX};
  for (int it = 0; it < ITERS; ++it) {
    int mid[4], c[4] = {0, 0, 0, 0};
#pragma unroll
    for (int i = 0; i < 4; ++i) {
      mid[i] = (lo4[i] + hi4[i]) >> 1;
      if (lo4[i] < hi4[i]) {
#pragma unroll
        for (int j = 0; j < NPT; ++j) c[i] += (dc[i][j] <= mid[i]) ? 1 : 0;
      }
    }
#pragma unroll
    for (int i = 0; i < 4; ++i)
#pragma unroll
      for (int off = 32; off > 0; off >>= 1)
        c[i] += __shfl_down(c[i], off, 64);
    if ((tid & 63) == 0) {
#pragma unroll
      for (int i = 0; i < 4; ++i) wsum4[tid >> 6][i] = c[i];
    }
    __syncthreads();
#pragma unroll
    for (int i = 0; i < 4; ++i) {
      if (lo4[i] < hi4[i]) {
        int tot = wsum4[0][i] + wsum4[1][i] + wsum4[2][i] + wsum4[3][i];
        if (tot >= TARGET) hi4[i] = mid[i]; else lo4[i] = mid[i] + 1;
      }
    }
    __syncthreads();
  }
  int T[4];
#pragma unroll
  for (int i = 0; i < 4; ++i) T[i] = lo4[i];
  if (tid == 0) cntS = 0;
  __syncthreads();
  int x0 = KRES - 1, x1 = 0, y0 = KRES - 1, y1 = 0;
#pragma unroll
  for (int i = 0; i < 4; ++i) {
    int rad = (int)sqrtf((float)T[i]);
    while ((rad + 1) * (rad + 1) <= T[i]) ++rad;
    while (rad > 0 && rad * rad > T[i]) --rad;
    x0 = min(x0, max(0, cxA[i] - rad));
    x1 = max(x1, min(KRES - 1, cxA[i] + rad));
    y0 = min(y0, max(0, cyA[i] - rad));
    y1 = max(y1, min(KRES - 1, cyA[i] + rad));
  }
  int W = x1 - x0 + 1, H = y1 - y0 + 1, tot = W * H;
  for (int p = tid; p < tot; p += 256) {
    int kx = x0 + p % W, ky = y0 + p / W;
    int d[4]; bool keep = false;
#pragma unroll
    for (int i = 0; i < 4; ++i) {
      int dx = cxA[i] - kx, dy = cyA[i] - ky;
      d[i] = dx * dx + dy * dy;
      keep = keep || (d[i] <= T[i]);
    }
    if (keep) {
      int s = atomicAdd(&cntS, 1);
      if (s < J2) {
        sidx[s] = ky * KRES + kx;
#pragma unroll
        for (int i = 0; i < 4; ++i) sdv[s][i] = d[i];
      }
    }
  }
  __syncthreads();
  int cnt = min(cntS, J2);
  int h = tid >> 5, lane = tid & 31;
  float sc = head_scale(rvec[h]) * (1.0f / (float)(1 << DSHIFT));
  float den[4] = {0.f, 0.f, 0.f, 0.f};
  for (int j = lane; j < cnt; j += 32) {
#pragma unroll
    for (int i = 0; i < 4; ++i)
      if (sdv[j][i] <= T[i]) den[i] += __expf(-sc * (float)sdv[j][i]);
  }
#pragma unroll
  for (int i = 0; i < 4; ++i) {
    float d0 = den[i];
#pragma unroll
    for (int off = 16; off > 0; off >>= 1) d0 += __shfl_down(d0, off, 32);
    if (lane == 0) denS[h][i] = d0;
  }
  __syncthreads();
  float inv[4];
#pragma unroll
  for (int i = 0; i < 4; ++i) inv[i] = 1.0f / denS[h][i];
  for (int j = lane; j < cnt; j += 32) {
    float w[4];
#pragma unroll
    for (int i = 0; i < 4; ++i)
      w[i] = (sdv[j][i] <= T[i]) ? __expf(-sc * (float)sdv[j][i]) * inv[i] : 0.f;
    float4v wv = {w[0], w[1], w[2], w[3]};
    *(float4v*)&wlist2[(((size_t)h * 256 + tile) * J2 + j) * 4] = wv;
  }
  if (tid == 0) kcnt2[tile] = cnt;
  if (h == 0)
    for (int j = lane; j < cnt; j += 32) klist2[(size_t)tile * J2 + j] = sidx[j];
}

// Merged: blocks [0,256) = down config, [256,512) = proc config.
__global__ __launch_bounds__(256) void k_klist_all(
    const float* __restrict__ down_r, const float* __restrict__ pa_r,
    int* __restrict__ klD2, int* __restrict__ cntD2, float* __restrict__ wlD2,
    int* __restrict__ klP2, int* __restrict__ cntP2, float* __restrict__ wlP2) {
  int tid = threadIdx.x;
  if (blockIdx.x < 256) {
    klist_body<64, 2, 13, 256, 16, 82, 13, 7938>(down_r, klD2, cntD2, wlD2,
                                                 blockIdx.x, tid);
  } else {
    klist_body<32, 1, 11, 256, 4, 103, 11, 1922>(pa_r, klP2, cntP2, wlP2,
                                                 blockIdx.x - 256, tid);
  }
}

// ---------------------------------------------------------------------------
// Tiled sparse attention: block = (2x2 q-tile, h), h in low bits (XCD).
// ---------------------------------------------------------------------------
template <int NK, int J2>
__global__ __launch_bounds__(256) void k_att3(
    const float* __restrict__ value,   // [h][NK][b*32+v]
    const int* __restrict__ klist2, const int* __restrict__ kcnt2,
    const float* __restrict__ wlist2, unsigned short* __restrict__ ohi,
    unsigned short* __restrict__ olo) {
  __shared__ int kls[J2];
  __shared__ float4v wls[J2];
  __shared__ float4v part[4][4][64];
  int blk = blockIdx.x;
  int tile = blk >> 3, h = blk & 7;
  int tid = threadIdx.x, g = tid & 63, s = tid >> 6;
  int cnt = kcnt2[tile];
  for (int j = tid; j < cnt; j += 256) {
    kls[j] = klist2[(size_t)tile * J2 + j];
    wls[j] = *(const float4v*)&wlist2[(((size_t)h * 256 + tile) * J2 + j) * 4];
  }
  __syncthreads();
  const float* vb = value + (size_t)h * NK * 256 + g * 4;
  float4v acc[4];
#pragma unroll
  for (int i = 0; i < 4; ++i) acc[i] = (float4v)0.0f;
  for (int j = s; j < cnt; j += 4) {
    int row = kls[j];
    float4v v = *(const float4v*)(vb + (size_t)row * 256);
    float4v w = wls[j];
    acc[0] += w.x * v;
    acc[1] += w.y * v;
    acc[2] += w.z * v;
    acc[3] += w.w * v;
  }
#pragma unroll
  for (int i = 0; i < 4; ++i) part[s][i][g] = acc[i];
  __syncthreads();
  if (tid < 64) {
    int g2 = tid;
    int ttx = tile & 15, tty = tile >> 4;
    int batch = g2 >> 3, v0 = (g2 & 7) * 4;
#pragma unroll
    for (int i = 0; i < 4; ++i) {
      float4v o4 = part[0][i][g2] + part[1][i][g2] + part[2][i][g2] +
                   part[3][i][g2];
      int q = (2 * tty + (i >> 1)) * 32 + 2 * ttx + (i & 1);
      size_t idx = ((size_t)batch * 1024 + q) * 256 + h * 32 + v0;
      ushort4v hv, lv;
#pragma unroll
      for (int c = 0; c < 4; ++c) {
        float oo = gelu_f(o4[c]);
        unsigned short hi, lo;
        split_bf(oo, hi, lo);
        hv[c] = hi; lv[c] = lo;
      }
      *(ushort4v*)(ohi + idx) = hv;
      *(ushort4v*)(olo + idx) = lv;
    }
  }
}

// ---------------------------------------------------------------------------
// Split-bf16 MFMA GEMM, 128x128 tile (big GEMMs, M=32768).
// ---------------------------------------------------------------------------
template <bool DUAL, int OL, bool GEL, bool OHILO>
__global__ __launch_bounds__(256) void k_mf(
    const unsigned short* __restrict__ A1hi, const unsigned short* __restrict__ A1lo,
    const unsigned short* __restrict__ W1hi, const unsigned short* __restrict__ W1lo,
    const unsigned short* __restrict__ A2hi, const unsigned short* __restrict__ A2lo,
    const unsigned short* __restrict__ W2hi, const unsigned short* __restrict__ W2lo,
    const float* __restrict__ bias, const float* __restrict__ bias2,
    float* __restrict__ outf, unsigned short* __restrict__ ohi,
    unsigned short* __restrict__ olo, int NS) {
  __shared__ unsigned short Ah[128][40], Al[128][40];
  __shared__ unsigned short Bh[128][40], Bl[128][40];
  int tid = threadIdx.x;
  int m0 = blockIdx.x * 128, n0 = blockIdx.y * 128;
  int w = tid >> 6, lane = tid & 63;
  int wm = (w >> 1) * 64, wn = (w & 1) * 64;
  int quad = lane >> 4, l16 = lane & 15;
  float4v acc[4][4];
#pragma unroll
  for (int i = 0; i < 4; ++i)
#pragma unroll
    for (int j = 0; j < 4; ++j) acc[i][j] = (float4v)0.0f;

  int srow = tid >> 1, skq = (tid & 1) * 16;
  const int KT = DUAL ? 512 : 256;
  for (int kk = 0; kk < KT; kk += 32) {
    const unsigned short *pAh, *pAl, *pWh, *pWl;
    int kb;
    if (DUAL && kk >= 256) {
      pAh = A2hi; pAl = A2lo; pWh = W2hi; pWl = W2lo; kb = kk - 256;
    } else {
      pAh = A1hi; pAl = A1lo; pWh = W1hi; pWl = W1lo; kb = kk;
    }
    {
      size_t ga = (size_t)(m0 + srow) * 256 + kb + skq;
      const uint4* pah = (const uint4*)(pAh + ga);
      const uint4* pal = (const uint4*)(pAl + ga);
      *(uint4*)&Ah[srow][skq] = pah[0];
      *(uint4*)&Ah[srow][skq + 8] = pah[1];
      *(uint4*)&Al[srow][skq] = pal[0];
      *(uint4*)&Al[srow][skq + 8] = pal[1];
      size_t gb = (size_t)(n0 + srow) * 256 + kb + skq;
      const uint4* pbh = (const uint4*)(pWh + gb);
      const uint4* pbl = (const uint4*)(pWl + gb);
      *(uint4*)&Bh[srow][skq] = pbh[0];
      *(uint4*)&Bh[srow][skq + 8] = pbh[1];
      *(uint4*)&Bl[srow][skq] = pbl[0];
      *(uint4*)&Bl[srow][skq + 8] = pbl[1];
    }
    __syncthreads();
    short8 ah[4], al[4], bh[4], bl[4];
#pragma unroll
    for (int s = 0; s < 4; ++s) {
      ah[s] = *(const short8*)&Ah[wm + s * 16 + l16][quad * 8];
      al[s] = *(const short8*)&Al[wm + s * 16 + l16][quad * 8];
      bh[s] = *(const short8*)&Bh[wn + s * 16 + l16][quad * 8];
      bl[s] = *(const short8*)&Bl[wn + s * 16 + l16][quad * 8];
    }
#pragma unroll
    for (int ms = 0; ms < 4; ++ms)
#pragma unroll
      for (int ns = 0; ns < 4; ++ns) {
        acc[ms][ns] = __builtin_amdgcn_mfma_f32_16x16x32_bf16(
            ah[ms], bh[ns], acc[ms][ns], 0, 0, 0);
        acc[ms][ns] = __builtin_amdgcn_mfma_f32_16x16x32_bf16(
            ah[ms], bl[ns], acc[ms][ns], 0, 0, 0);
        acc[ms][ns] = __builtin_amdgcn_mfma_f32_16x16x32_bf16(
            al[ms], bh[ns], acc[ms][ns], 0, 0, 0);
      }
    __syncthreads();
  }
#pragma unroll
  for (int ms = 0; ms < 4; ++ms) {
#pragma unroll
    for (int ns = 0; ns < 4; ++ns) {
      int n = n0 + wn + ns * 16 + l16;
      float bv = bias ? bias[n] : 0.0f;
      if (DUAL && bias2) bv += bias2[n];
#pragma unroll
      for (int r = 0; r < 4; ++r) {
        int m = m0 + wm + ms * 16 + quad * 4 + r;
        float c = acc[ms][ns][r] + bv;
        if (GEL) c = gelu_f(c);
        if (OHILO) {
          unsigned short chi, clo;
          split_bf(c, chi, clo);
          ohi[(size_t)m * 256 + n] = chi;
          olo[(size_t)m * 256 + n] = clo;
        } else if (OL == 0) {
          outf[(size_t)m * 256 + n] = c;
        } else {
          int N = 1 << NS;
          int bb = m >> NS, rr = m & (N - 1);
          outf[(((size_t)(n >> 5) * N + rr) * 8 + bb) * 32 + (n & 31)] = c;
        }
      }
    }
  }
}

// ---------------------------------------------------------------------------
// Decoder fc1+fc2 fused: 128x128 MFMA core; epilogue reduces
// sum_n gelu(fc1+b1)*w2[n] via shfl_xor, atomicAdd into out (pre-init b2).
// ---------------------------------------------------------------------------
__global__ __launch_bounds__(256) void k_mf_dec(
    const unsigned short* __restrict__ A1hi, const unsigned short* __restrict__ A1lo,
    const unsigned short* __restrict__ W1hi, const unsigned short* __restrict__ W1lo,
    const float* __restrict__ b1, const float* __restrict__ w2,
    float* __restrict__ out) {
  __shared__ unsigned short Ah[128][40], Al[128][40];
  __shared__ unsigned short Bh[128][40], Bl[128][40];
  int tid = threadIdx.x;
  int m0 = blockIdx.x * 128, n0 = blockIdx.y * 128;
  int w = tid >> 6, lane = tid & 63;
  int wm = (w >> 1) * 64, wn = (w & 1) * 64;
  int quad = lane >> 4, l16 = lane & 15;
  float4v acc[4][4];
#pragma unroll
  for (int i = 0; i < 4; ++i)
#pragma unroll
    for (int j = 0; j < 4; ++j) acc[i][j] = (float4v)0.0f;

  int srow = tid >> 1, skq = (tid & 1) * 16;
  for (int kk = 0; kk < 256; kk += 32) {
    {
      size_t ga = (size_t)(m0 + srow) * 256 + kk + skq;
      const uint4* pah = (const uint4*)(A1hi + ga);
      const uint4* pal = (const uint4*)(A1lo + ga);
      *(uint4*)&Ah[srow][skq] = pah[0];
      *(uint4*)&Ah[srow][skq + 8] = pah[1];
      *(uint4*)&Al[srow][skq] = pal[0];
      *(uint4*)&Al[srow][skq + 8] = pal[1];
      size_t gb = (size_t)(n0 + srow) * 256 + kk + skq;
      const uint4* pbh = (const uint4*)(W1hi + gb);
      const uint4* pbl = (const uint4*)(W1lo + gb);
      *(uint4*)&Bh[srow][skq] = pbh[0];
      *(uint4*)&Bh[srow][skq + 8] = pbh[1];
      *(uint4*)&Bl[srow][skq] = pbl[0];
      *(uint4*)&Bl[srow][skq + 8] = pbl[1];
    }
    __syncthreads();
    short8 ah[4], al[4], bh[4], bl[4];
#pragma unroll
    for (int s = 0; s < 4; ++s) {
      ah[s] = *(const short8*)&Ah[wm + s * 16 + l16][quad * 8];
      al[s] = *(const short8*)&Al[wm + s * 16 + l16][quad * 8];
      bh[s] = *(const short8*)&Bh[wn + s * 16 + l16][quad * 8];
      bl[s] = *(const short8*)&Bl[wn + s * 16 + l16][quad * 8];
    }
#pragma unroll
    for (int ms = 0; ms < 4; ++ms)
#pragma unroll
      for (int ns = 0; ns < 4; ++ns) {
        acc[ms][ns] = __builtin_amdgcn_mfma_f32_16x16x32_bf16(
            ah[ms], bh[ns], acc[ms][ns], 0, 0, 0);
        acc[ms][ns] = __builtin_amdgcn_mfma_f32_16x16x32_bf16(
            ah[ms], bl[ns], acc[ms][ns], 0, 0, 0);
        acc[ms][ns] = __builtin_amdgcn_mfma_f32_16x16x32_bf16(
            al[ms], bh[ns], acc[ms][ns], 0, 0, 0);
      }
    __syncthreads();
  }
#pragma unroll
  for (int ms = 0; ms < 4; ++ms) {
#pragma unroll
    for (int r = 0; r < 4; ++r) {
      float p = 0.0f;
#pragma unroll
      for (int ns = 0; ns < 4; ++ns) {
        int n = n0 + wn + ns * 16 + l16;
        float c = gelu_f(acc[ms][ns][r] + b1[n]);
        p += c * w2[n];
      }
      p += __shfl_xor(p, 1, 64);
      p += __shfl_xor(p, 2, 64);
      p += __shfl_xor(p, 4, 64);
      p += __shfl_xor(p, 8, 64);
      if (l16 == 0) {
        int m = m0 + wm + ms * 16 + quad * 4 + r;
        atomicAdd(&out[m], p);
      }
    }
  }
}

// ---------------------------------------------------------------------------
// Split-bf16 MFMA GEMM, 64x64 tile (medium GEMMs, M=8192 -> 512 blocks).
// ---------------------------------------------------------------------------
template <bool DUAL, int OL, bool GEL, bool OHILO>
__global__ __launch_bounds__(256) void k_mf2(
    const unsigned short* __restrict__ A1hi, const unsigned short* __restrict__ A1lo,
    const unsigned short* __restrict__ W1hi, const unsigned short* __restrict__ W1lo,
    const unsigned short* __restrict__ A2hi, const unsigned short* __restrict__ A2lo,
    const unsigned short* __restrict__ W2hi, const unsigned short* __restrict__ W2lo,
    const float* __restrict__ bias, const float* __restrict__ bias2,
    float* __restrict__ outf, unsigned short* __restrict__ ohi,
    unsigned short* __restrict__ olo, int NS) {
  __shared__ unsigned short Ah[64][40], Al[64][40];
  __shared__ unsigned short Bh[64][40], Bl[64][40];
  int tid = threadIdx.x;
  int m0 = blockIdx.x * 64, n0 = blockIdx.y * 64;
  int w = tid >> 6, lane = tid & 63;
  int wm = (w >> 1) * 32, wn = (w & 1) * 32;
  int quad = lane >> 4, l16 = lane & 15;
  float4v acc[2][2];
#pragma unroll
  for (int i = 0; i < 2; ++i)
#pragma unroll
    for (int j = 0; j < 2; ++j) acc[i][j] = (float4v)0.0f;

  int srow = tid >> 2, skq = (tid & 3) * 8;
  const int KT = DUAL ? 512 : 256;
  for (int kk = 0; kk < KT; kk += 32) {
    const unsigned short *pAh, *pAl, *pWh, *pWl;
    int kb;
    if (DUAL && kk >= 256) {
      pAh = A2hi; pAl = A2lo; pWh = W2hi; pWl = W2lo; kb = kk - 256;
    } else {
      pAh = A1hi; pAl = A1lo; pWh = W1hi; pWl = W1lo; kb = kk;
    }
    {
      size_t ga = (size_t)(m0 + srow) * 256 + kb + skq;
      *(uint4*)&Ah[srow][skq] = *(const uint4*)(pAh + ga);
      *(uint4*)&Al[srow][skq] = *(const uint4*)(pAl + ga);
      size_t gb = (size_t)(n0 + srow) * 256 + kb + skq;
      *(uint4*)&Bh[srow][skq] = *(const uint4*)(pWh + gb);
      *(uint4*)&Bl[srow][skq] = *(const uint4*)(pWl + gb);
    }
    __syncthreads();
    short8 ah[2], al[2], bh[2], bl[2];
#pragma unroll
    for (int s = 0; s < 2; ++s) {
      ah[s] = *(const short8*)&Ah[wm + s * 16 + l16][quad * 8];
      al[s] = *(const short8*)&Al[wm + s * 16 + l16][quad * 8];
      bh[s] = *(const short8*)&Bh[wn + s * 16 + l16][quad * 8];
      bl[s] = *(const short8*)&Bl[wn + s * 16 + l16][quad * 8];
    }
#pragma unroll
    for (int ms = 0; ms < 2; ++ms)
#pragma unroll
      for (int ns = 0; ns < 2; ++ns) {
        acc[ms][ns] = __builtin_amdgcn_mfma_f32_16x16x32_bf16(
            ah[ms], bh[ns], acc[ms][ns], 0, 0, 0);
        acc[ms][ns] = __builtin_amdgcn_mfma_f32_16x16x32_bf16(
            ah[ms], bl[ns], acc[ms][ns], 0, 0, 0);
        acc[ms][ns] = __builtin_amdgcn_mfma_f32_16x16x32_bf16(
            al[ms], bh[ns], acc[ms][ns], 0, 0, 0);
      }
    __syncthreads();
  }
#pragma unroll
  for (int ms = 0; ms < 2; ++ms) {
#pragma unroll
    for (int ns = 0; ns < 2; ++ns) {
      int n = n0 + wn + ns * 16 + l16;
      float bv = bias ? bias[n] : 0.0f;
      if (DUAL && bias2) bv += bias2[n];
#pragma unroll
      for (int r = 0; r < 4; ++r) {
        int m = m0 + wm + ms * 16 + quad * 4 + r;
        float c = acc[ms][ns][r] + bv;
        if (GEL) c = gelu_f(c);
        if (OHILO) {
          unsigned short chi, clo;
          split_bf(c, chi, clo);
          ohi[(size_t)m * 256 + n] = chi;
          olo[(size_t)m * 256 + n] = clo;
        } else if (OL == 0) {
          outf[(size_t)m * 256 + n] = c;
        } else {
          int N = 1 << NS;
          int bb = m >> NS, rr = m & (N - 1);
          outf[(((size_t)(n >> 5) * N + rr) * 8 + bb) * 32 + (n & 31)] = c;
        }
      }
    }
  }
}

// ---------------------------------------------------------------------------
// Separable up-attention stage 1 (qx split 2x for occupancy).
// ---------------------------------------------------------------------------
__global__ __launch_bounds__(256) void k_up_s1(
    const float* __restrict__ value,  // [h][1024][bv]
    const float* __restrict__ rvec, float* __restrict__ T) {
  __shared__ float AxL[32][33];
  int ky = blockIdx.x, h = blockIdx.y, qx0 = blockIdx.z * 32;
  int tid = threadIdx.x;
  float sc = head_scale(rvec[h]) * (1.0f / 8192.0f);
  float v[32];
  const float* vb = value + ((size_t)h * 1024 + ky * 32) * 256 + tid;
#pragma unroll
  for (int kx = 0; kx < 32; ++kx) v[kx] = vb[kx * 256];
  if (tid < 32) {
    int qx = qx0 + tid, dxmin = qx & 1;
    for (int kx = 0; kx < 32; ++kx) {
      int dx = qx - 2 * kx;
      AxL[tid][kx] = __expf(-sc * (float)(dx * dx - dxmin));
    }
  }
  __syncthreads();
  for (int qq = 0; qq < 32; ++qq) {
    int qx = qx0 + qq;
    float acc = 0.f;
#pragma unroll
    for (int kx = 0; kx < 32; ++kx) acc += AxL[qq][kx] * v[kx];
    T[(((size_t)h * 64 + qx) * 32 + ky) * 256 + tid] = acc;
  }
}

// ---------------------------------------------------------------------------
// Separable up-attention stage 2 -> bf16 hi/lo (feeds dec-fc1 MFMA).
// ---------------------------------------------------------------------------
__global__ __launch_bounds__(256) void k_up_s2(
    const float* __restrict__ T, const float* __restrict__ rvec,
    unsigned short* __restrict__ ohi, unsigned short* __restrict__ olo) {
  __shared__ float AyL[64][33];
  __shared__ float Sy[64];
  __shared__ float SxS;
  int qx = blockIdx.x, h = blockIdx.y, tid = threadIdx.x;
  float sc = head_scale(rvec[h]) * (1.0f / 8192.0f);
  float t[32];
  const float* tb = T + ((size_t)h * 64 + qx) * 32 * 256 + tid;
#pragma unroll
  for (int ky = 0; ky < 32; ++ky) t[ky] = tb[ky * 256];
  if (tid < 64) {
    int qy = tid, dymin = qy & 1;
    float s = 0.f;
    for (int ky = 0; ky < 32; ++ky) {
      int dy = qy - 2 * ky;
      float e = __expf(-sc * (float)(dy * dy - dymin));
      AyL[qy][ky] = e;
      s += e;
    }
    Sy[qy] = s;
  } else if (tid >= 64 && tid < 96) {
    int kx = tid - 64, dxmin = qx & 1;
    int dx = qx - 2 * kx;
    float e = __expf(-sc * (float)(dx * dx - dxmin));
#pragma unroll
    for (int off = 16; off > 0; off >>= 1) e += __shfl_down(e, off, 32);
    if (kx == 0) SxS = e;
  }
  __syncthreads();
  float invSx = 1.0f / SxS;
  int b = tid >> 5, v = tid & 31;
  size_t base = ((size_t)b * 4096 + qx) * 256 + h * 32 + v;
  for (int qy = 0; qy < 64; ++qy) {
    float acc = 0.f;
#pragma unroll
    for (int ky = 0; ky < 32; ++ky) acc += AyL[qy][ky] * t[ky];
    float o = gelu_f(acc * invSx / Sy[qy]);
    unsigned short hi, lo;
    split_bf(o, hi, lo);
    size_t idx = base + (size_t)qy * 64 * 256;
    ohi[idx] = hi;
    olo[idx] = lo;
  }
}

// ---------------------------------------------------------------------------
extern "C" void kernel_launch(void* const* d_in, const int* in_sizes, int n_in,
                              void* d_out, int out_size, void* d_ws,
                              size_t ws_size, hipStream_t stream) {
  const float* x      = (const float*)d_in[0];
  const float* en_w   = (const float*)d_in[1];
  const float* en_b   = (const float*)d_in[2];
  const float* down_r = (const float*)d_in[3];
  const float* down_w = (const float*)d_in[4];
  const float* pa_r   = (const float*)d_in[5];
  const float* pa_w   = (const float*)d_in[6];
  const float* mlp1_w = (const float*)d_in[7];
  const float* mlp1_b = (const float*)d_in[8];
  const float* mlp2_w = (const float*)d_in[9];
  const float* mlp2_b = (const float*)d_in[10];
  const float* res_w  = (const float*)d_in[11];
  const float* res_b  = (const float*)d_in[12];
  const float* up_r   = (const float*)d_in[13];
  const float* up_w   = (const float*)d_in[14];
  const float* de1_w  = (const float*)d_in[15];
  const float* de1_b  = (const float*)d_in[16];
  const float* de2_w  = (const float*)d_in[17];
  const float* de2_b  = (const float*)d_in[18];
  float* out = (float*)d_out;

  constexpr int J2 = 256;
  float* ws = (float*)d_ws;
  // [0, 8388608): enc / up_s2 activations, bf16 hi/lo (32768x256 each)
  unsigned short* Ahi = (unsigned short*)ws;
  unsigned short* Alo = Ahi + 8388608;
  // [8388608, 16777216): B fp32 — down value / proc+up value / T
  float* B = ws + 8388608;
  float* Tbuf = B + 2097152;
  // [16777216, 25165824): 8 activation hi/lo buffers, each 2097152 ushorts
  unsigned short* hAhi = (unsigned short*)(ws + 16777216);
  unsigned short* hAlo = hAhi + 2097152;
  unsigned short* hBhi = hAlo + 2097152;
  unsigned short* hBlo = hBhi + 2097152;
  unsigned short* pahi = hBlo + 2097152;
  unsigned short* palo = pahi + 2097152;
  unsigned short* m1hi = palo + 2097152;
  unsigned short* m1lo = m1hi + 2097152;
  // [25165824, ...): misc — AFTER all activation buffers.
  int* cntD2 = (int*)(ws + 25165824);
  int* cntP2 = cntD2 + 256;
  int* klD2 = cntP2 + 256;              // [256*J2]
  int* klP2 = klD2 + 256 * J2;
  float* wlD2 = (float*)(klP2 + 256 * J2);  // [8*256*J2*4] = 2097152 floats
  float* wlP2 = wlD2 + 2097152;
  unsigned short* Whi = (unsigned short*)(wlP2 + 2097152);  // 1245184 each
  unsigned short* Wlo = Whi + 1245184;
  const int WO_DOWN = 0, WO_DE1 = 65536, WO_UP = 131072, WO_PA = 196608,
            WO_MLP1 = 458752, WO_MLP2 = 720896, WO_RES = 983040;

  // 1. merged pre-pass: encoder + weight split + out init
  k_pre<<<37760, 256, 0, stream>>>(x, en_w, en_b, Ahi, Alo, down_w, de1_w,
                                   up_w, pa_w, mlp1_w, mlp2_w, res_w, Whi,
                                   Wlo, out, de2_b);
  // 2. merged tiled key lists (fused thresholds), both configs
  k_klist_all<<<512, 256, 0, stream>>>(down_r, pa_r, klD2, cntD2, wlD2, klP2,
                                       cntP2, wlP2);
  // 3. down: value MFMA -> B [h][4096][bv]; tiled sparse att -> hA (hi/lo)
  k_mf<false, 1, false, false><<<dim3(256, 2), 256, 0, stream>>>(
      Ahi, Alo, Whi + WO_DOWN, Wlo + WO_DOWN, nullptr, nullptr, nullptr,
      nullptr, nullptr, nullptr, B, nullptr, nullptr, 12);
  k_att3<4096, J2><<<2048, 256, 0, stream>>>(B, klD2, cntD2, wlD2, hAhi, hAlo);
  // 4. processor blocks, h ping-pong hA <-> hB (64x64-tile MFMA)
  for (int i = 0; i < 4; ++i) {
    const unsigned short* hih = (i & 1) ? hBhi : hAhi;
    const unsigned short* hil = (i & 1) ? hBlo : hAlo;
    unsigned short* hoh = (i & 1) ? hAhi : hBhi;
    unsigned short* hol = (i & 1) ? hAlo : hBlo;
    k_mf2<false, 1, false, false><<<dim3(128, 4), 256, 0, stream>>>(
        hih, hil, Whi + WO_PA + i * 65536, Wlo + WO_PA + i * 65536, nullptr,
        nullptr, nullptr, nullptr, nullptr, nullptr, B, nullptr, nullptr, 10);
    k_att3<1024, J2><<<2048, 256, 0, stream>>>(B, klP2, cntP2, wlP2, pahi,
                                               palo);
    k_mf2<false, 0, true, true><<<dim3(128, 4), 256, 0, stream>>>(
        pahi, palo, Whi + WO_MLP1 + i * 65536, Wlo + WO_MLP1 + i * 65536,
        nullptr, nullptr, nullptr, nullptr, mlp1_b + i * 256, nullptr, nullptr,
        m1hi, m1lo, 0);
    k_mf2<true, 0, true, true><<<dim3(128, 4), 256, 0, stream>>>(
        m1hi, m1lo, Whi + WO_MLP2 + i * 65536, Wlo + WO_MLP2 + i * 65536, hih,
        hil, Whi + WO_RES + i * 65536, Wlo + WO_RES + i * 65536,
        mlp2_b + i * 256, res_b + i * 256, nullptr, hoh, hol, 0);
  }
  // 5. up: value MFMA -> B [h][1024][bv]; separable attention
  k_mf2<false, 1, false, false><<<dim3(128, 4), 256, 0, stream>>>(
      hAhi, hAlo, Whi + WO_UP, Wlo + WO_UP, nullptr, nullptr, nullptr, nullptr,
      nullptr, nullptr, B, nullptr, nullptr, 10);
  k_up_s1<<<dim3(32, 8, 2), 256, 0, stream>>>(B, up_r, Tbuf);
  k_up_s2<<<dim3(64, 8), 256, 0, stream>>>(Tbuf, up_r, Ahi, Alo);
  // 6. decoder: fc1+fc2 fused MFMA (out pre-initialized by k_pre)
  k_mf_dec<<<dim3(256, 2), 256, 0, stream>>>(Ahi, Alo, Whi + WO_DE1,
                                             Wlo + WO_DE1, de1_b, de2_w, out);
}